// Round 1
// baseline (49.357 us; speedup 1.0000x reference)
//
#include <hip/hip_runtime.h>

// PatchMMD: x,y are (64,1,64,64) fp32. For pairs (i,j):
//   D(i,j,p,q) = sum_{3x3 window at (p,q)} (A_i - B_j)^2   (VALID -> 62x62)
//   K = exp(-D / (2*(0.5*9)^2)) = exp(-D/40.5)
// out = offdiag_mean(Kxx) - 2*mean(Kxy) + offdiag_mean(Kyy)
// Accumulate in fp64 (result is a ~1e-4 cancellation of ~0.64-scale means).

#define HW 4096      // 64*64 pixels per image
#define SROW 66      // padded LDS row stride (64 + 2 pad cols, also kills pow2 stride)
#define OUT_W 62

__global__ __launch_bounds__(256) void mmd_pair_kernel(
    const float* __restrict__ x, const float* __restrict__ y,
    double* __restrict__ partials)
{
    const int bid  = blockIdx.x;
    const int type = bid >> 12;      // 0: xx, 1: yy, 2: xy
    const int pair = bid & 4095;
    const int i = pair >> 6;
    const int j = pair & 63;
    const int t = threadIdx.x;

    // xx/yy exclude the diagonal: write 0 partial and leave (uniform branch).
    if (type != 2 && i == j) {
        if (t == 0) partials[bid] = 0.0;
        return;
    }

    const float* __restrict__ A = (type == 1 ? y : x) + i * HW;
    const float* __restrict__ B = (type == 0 ? x : y) + j * HW;

    __shared__ float s[64 * SROW];
    __shared__ float hs[64 * SROW];
    __shared__ double wsum[4];

    // zero the 2 pad columns so the horizontal pass can run unconditionally
    if (t < 128) {
        int r = t >> 1, c = 64 + (t & 1);
        s[r * SROW + c] = 0.0f;
    }

    // per-pixel squared diff -> LDS
    #pragma unroll
    for (int k = 0; k < 16; ++k) {
        int e = t + k * 256;           // coalesced
        int r = e >> 6, c = e & 63;
        float d = A[e] - B[e];
        s[r * SROW + c] = d * d;
    }
    __syncthreads();

    // horizontal 3-sum: hs[r][c] = s[r][c] + s[r][c+1] + s[r][c+2]
    // (c >= 62 entries are harmless garbage-with-zero-pad, never consumed)
    #pragma unroll
    for (int k = 0; k < 16; ++k) {
        int e = t + k * 256;
        int r = e >> 6, c = e & 63;
        const float* sr = s + r * SROW + c;
        hs[r * SROW + c] = sr[0] + sr[1] + sr[2];
    }
    __syncthreads();

    // vertical 3-sum + exp, fp64 accumulate
    const float NEG_SCALE = -1.0f / 40.5f;
    double lsum = 0.0;
    #pragma unroll
    for (int k = 0; k < 16; ++k) {
        int e = t + k * 256;
        int p = e >> 6, q = e & 63;    // within a wave: fixed p, q = lane -> conflict-free
        if (p < OUT_W && q < OUT_W) {
            const float* hp = hs + p * SROW + q;
            float D = hp[0] + hp[SROW] + hp[2 * SROW];
            lsum += (double)__expf(D * NEG_SCALE);
        }
    }

    // deterministic wave reduce (64 lanes), then 4 wave partials
    #pragma unroll
    for (int off = 32; off > 0; off >>= 1)
        lsum += __shfl_down(lsum, off);
    const int lane = t & 63, wid = t >> 6;
    if (lane == 0) wsum[wid] = lsum;
    __syncthreads();
    if (t == 0)
        partials[bid] = wsum[0] + wsum[1] + wsum[2] + wsum[3];
}

__global__ __launch_bounds__(256) void mmd_reduce_kernel(
    const double* __restrict__ partials, float* __restrict__ out)
{
    const int t = threadIdx.x;
    double acc0 = 0.0, acc1 = 0.0, acc2 = 0.0;
    #pragma unroll
    for (int k = 0; k < 16; ++k) {
        int e = t + k * 256;
        acc0 += partials[e];            // xx (off-diag; diag slots are 0)
        acc1 += partials[4096 + e];     // yy
        acc2 += partials[8192 + e];     // xy (all pairs)
    }
    __shared__ double w[3][4];
    const int lane = t & 63, wid = t >> 6;
    double v;
    v = acc0;
    #pragma unroll
    for (int off = 32; off > 0; off >>= 1) v += __shfl_down(v, off);
    if (lane == 0) w[0][wid] = v;
    v = acc1;
    #pragma unroll
    for (int off = 32; off > 0; off >>= 1) v += __shfl_down(v, off);
    if (lane == 0) w[1][wid] = v;
    v = acc2;
    #pragma unroll
    for (int off = 32; off > 0; off >>= 1) v += __shfl_down(v, off);
    if (lane == 0) w[2][wid] = v;
    __syncthreads();
    if (t == 0) {
        double sxx = w[0][0] + w[0][1] + w[0][2] + w[0][3];
        double syy = w[1][0] + w[1][1] + w[1][2] + w[1][3];
        double sxy = w[2][0] + w[2][1] + w[2][2] + w[2][3];
        const double cnt_off = 64.0 * 63.0 * 62.0 * 62.0;   // N*(N-1)*h*w
        const double cnt_all = 64.0 * 64.0 * 62.0 * 62.0;   // N*N*h*w
        out[0] = (float)(sxx / cnt_off - 2.0 * sxy / cnt_all + syy / cnt_off);
    }
}

extern "C" void kernel_launch(void* const* d_in, const int* in_sizes, int n_in,
                              void* d_out, int out_size, void* d_ws, size_t ws_size,
                              hipStream_t stream) {
    const float* x = (const float*)d_in[0];
    const float* y = (const float*)d_in[1];
    float* out = (float*)d_out;
    double* partials = (double*)d_ws;   // 12288 doubles = 96 KiB

    mmd_pair_kernel<<<3 * 4096, 256, 0, stream>>>(x, y, partials);
    mmd_reduce_kernel<<<1, 256, 0, stream>>>(partials, out);
}

// Round 2
// 33.818 us; speedup vs baseline: 1.4595x; 1.4595x over previous
//
#include <hip/hip_runtime.h>

// PatchMMD: x,y are (64,1,64,64) fp32. For pairs (i,j):
//   D(i,j,p,q) = sum_{3x3 window at (p,q)} (A_i - B_j)^2   (VALID -> 62x62)
//   K = exp(-D / (2*(0.5*9)^2)) = exp(-D/40.5)
// out = offdiag_mean(Kxx) - 2*mean(Kxy) + offdiag_mean(Kyy)
//
// Round 2 structure:
//  - symmetry: xx/yy computed only for i<j (2016 pairs each), doubled in reduce
//  - single LDS array (64x68 padded, 17 KB) -> 8 blocks/CU (32-wave cap)
//  - fused box filter: horizontal 3-sum per row, vertical 3-sum slid in registers
//  - float4 global loads + b128 LDS stores; exp via single mul + v_exp (exp2)
//  - fp64 accumulation (result is a ~1e-4 cancellation of ~0.64-scale means)

#define HW 4096      // 64*64 pixels per image
#define SROW 68      // padded LDS row stride: 16B-aligned float4 stores, conflict-free
#define NPAIR_TRI 2016   // 64*63/2

#if __has_builtin(__builtin_amdgcn_exp2f)
#define EXP2F(v) __builtin_amdgcn_exp2f(v)
#else
#define EXP2F(v) __expf((v) * 0.69314718055994530942f)
#endif

__global__ __launch_bounds__(256) void mmd_pair_kernel(
    const float* __restrict__ x, const float* __restrict__ y,
    double* __restrict__ partials)
{
    const int bid = blockIdx.x;
    const int t   = threadIdx.x;

    // block -> (type, i, j). [0,2016): xx i<j; [2016,4032): yy i<j; rest: xy all.
    int type, i, j;
    if (bid < 2 * NPAIR_TRI) {
        type = (bid < NPAIR_TRI) ? 0 : 1;
        int k = bid - type * NPAIR_TRI;
        int ii = 0;
        while (k >= 63 - ii) { k -= 63 - ii; ++ii; }   // uniform scalar loop
        i = ii; j = ii + 1 + k;
    } else {
        type = 2;
        int pair = bid - 2 * NPAIR_TRI;
        i = pair >> 6; j = pair & 63;
    }

    const float* __restrict__ A = (type == 1 ? y : x) + i * HW;
    const float* __restrict__ B = (type == 0 ? x : y) + j * HW;

    __shared__ float s[64 * SROW];
    __shared__ double wsum[4];

    // pass 1: per-pixel squared diff -> LDS, float4-wide
    const float4* __restrict__ A4 = reinterpret_cast<const float4*>(A);
    const float4* __restrict__ B4 = reinterpret_cast<const float4*>(B);
    #pragma unroll
    for (int k = 0; k < 4; ++k) {
        int e4 = t + k * 256;            // 0..1023, coalesced
        float4 a = A4[e4];
        float4 b = B4[e4];
        float4 d;
        d.x = a.x - b.x; d.y = a.y - b.y; d.z = a.z - b.z; d.w = a.w - b.w;
        d.x *= d.x; d.y *= d.y; d.z *= d.z; d.w *= d.w;
        int r  = e4 >> 4;
        int c4 = (e4 & 15) << 2;
        *reinterpret_cast<float4*>(&s[r * SROW + c4]) = d;   // 16B-aligned (SROW%4==0)
    }
    __syncthreads();

    // pass 2: fused 3x3 box + exp. Wave w owns row strip, lane q owns a column.
    // h(r) = s[r][q]+s[r][q+1]+s[r][q+2]; D(p) = h(p)+h(p+1)+h(p+2).
    const int lane = t & 63, wid = t >> 6;
    const int q = lane;
    const int p0 = wid * 16;                       // strips 16,16,16,14
    const int r_end = (p0 + 18 < 64) ? p0 + 18 : 64;
    const float NEG_SCALE = -1.0f / (40.5f * 0.69314718055994530942f);  // exp2 scale
    const bool active = (q < 62);

    double lsum = 0.0;
    float hm2 = 0.0f, hm1 = 0.0f;
    #pragma unroll 4
    for (int r = p0; r < r_end; ++r) {
        const float* sr = s + r * SROW + q;
        float h = sr[0] + sr[1] + sr[2];
        if (r >= p0 + 2 && active) {
            float D = hm2 + hm1 + h;
            lsum += (double)EXP2F(D * NEG_SCALE);
        }
        hm2 = hm1; hm1 = h;
    }

    // deterministic wave reduce (64 lanes), then 4 wave partials
    #pragma unroll
    for (int off = 32; off > 0; off >>= 1)
        lsum += __shfl_down(lsum, off);
    if (lane == 0) wsum[wid] = lsum;
    __syncthreads();
    if (t == 0)
        partials[bid] = wsum[0] + wsum[1] + wsum[2] + wsum[3];
}

__global__ __launch_bounds__(256) void mmd_reduce_kernel(
    const double* __restrict__ partials, float* __restrict__ out)
{
    const int t = threadIdx.x;
    double a0 = 0.0, a1 = 0.0, a2 = 0.0;
    for (int e = t; e < NPAIR_TRI; e += 256) a0 += partials[e];                  // xx, i<j
    for (int e = t; e < NPAIR_TRI; e += 256) a1 += partials[NPAIR_TRI + e];      // yy, i<j
    for (int e = t; e < 4096;      e += 256) a2 += partials[2 * NPAIR_TRI + e];  // xy, all

    __shared__ double w[3][4];
    const int lane = t & 63, wid = t >> 6;
    double v;
    v = a0;
    #pragma unroll
    for (int off = 32; off > 0; off >>= 1) v += __shfl_down(v, off);
    if (lane == 0) w[0][wid] = v;
    v = a1;
    #pragma unroll
    for (int off = 32; off > 0; off >>= 1) v += __shfl_down(v, off);
    if (lane == 0) w[1][wid] = v;
    v = a2;
    #pragma unroll
    for (int off = 32; off > 0; off >>= 1) v += __shfl_down(v, off);
    if (lane == 0) w[2][wid] = v;
    __syncthreads();
    if (t == 0) {
        double sxx = w[0][0] + w[0][1] + w[0][2] + w[0][3];   // half of off-diag sum
        double syy = w[1][0] + w[1][1] + w[1][2] + w[1][3];
        double sxy = w[2][0] + w[2][1] + w[2][2] + w[2][3];
        const double cnt_off = 64.0 * 63.0 * 62.0 * 62.0;     // N*(N-1)*h*w
        const double cnt_all = 64.0 * 64.0 * 62.0 * 62.0;     // N*N*h*w
        out[0] = (float)(2.0 * sxx / cnt_off - 2.0 * sxy / cnt_all + 2.0 * syy / cnt_off);
    }
}

extern "C" void kernel_launch(void* const* d_in, const int* in_sizes, int n_in,
                              void* d_out, int out_size, void* d_ws, size_t ws_size,
                              hipStream_t stream) {
    const float* x = (const float*)d_in[0];
    const float* y = (const float*)d_in[1];
    float* out = (float*)d_out;
    double* partials = (double*)d_ws;   // 8128 doubles = 63.5 KiB

    mmd_pair_kernel<<<2 * NPAIR_TRI + 4096, 256, 0, stream>>>(x, y, partials);
    mmd_reduce_kernel<<<1, 256, 0, stream>>>(partials, out);
}

// Round 3
// 30.231 us; speedup vs baseline: 1.6327x; 1.1187x over previous
//
#include <hip/hip_runtime.h>

// PatchMMD: x,y are (64,1,64,64) fp32. For pairs (i,j):
//   D(i,j,p,q) = sum_{3x3 window at (p,q)} (A_i - B_j)^2   (VALID -> 62x62)
//   K = exp(-D / (2*(0.5*9)^2)) = exp(-D/40.5)
// out = offdiag_mean(Kxx) - 2*mean(Kxy) + offdiag_mean(Kyy)
//
// Round 3 structure:
//  - symmetry: xx/yy only for i<j (2016 pairs each), doubled in reduce
//  - pass 1: d^2 in regs, horizontal 3-sum h via 2 cross-lane shuffles,
//    h stored to LDS as float4 (the ONLY LDS array, 17.4 KB -> 8 blocks/CU)
//  - pass 2: ds_read_b128 of h, vertical 3-sum in regs, exp2, float4 acc
//  - boundary cols poisoned with 1e30 in pass 1 (exp -> exactly 0)
//  - fp64 only from per-thread partials onward (4-deep fp32 chains are
//    ~1e-10 relative on the means; threshold needs ~1e-6)

#define HW 4096          // 64*64 pixels per image
#define HS 68            // h LDS row stride in floats (16B-aligned, bank-staggered)
#define NPAIR_TRI 2016   // 64*63/2

#if __has_builtin(__builtin_amdgcn_exp2f)
#define EXP2F(v) __builtin_amdgcn_exp2f(v)
#else
#define EXP2F(v) __expf((v) * 0.69314718055994530942f)
#endif

__global__ __launch_bounds__(256) void mmd_pair_kernel(
    const float* __restrict__ x, const float* __restrict__ y,
    double* __restrict__ partials)
{
    const int bid = blockIdx.x;
    const int t   = threadIdx.x;

    // block -> (type, i, j). [0,2016): xx i<j; [2016,4032): yy i<j; rest: xy all.
    int type, i, j;
    if (bid < 2 * NPAIR_TRI) {
        type = (bid < NPAIR_TRI) ? 0 : 1;
        int k = bid - type * NPAIR_TRI;
        int ii = 0;
        while (k >= 63 - ii) { k -= 63 - ii; ++ii; }   // uniform scalar loop
        i = ii; j = ii + 1 + k;
    } else {
        type = 2;
        int pair = bid - 2 * NPAIR_TRI;
        i = pair >> 6; j = pair & 63;
    }

    const float* __restrict__ A = (type == 1 ? y : x) + i * HW;
    const float* __restrict__ B = (type == 0 ? x : y) + j * HW;

    __shared__ float hl[64 * HS];
    __shared__ double wsum[4];

    // pass 1: d^2 in regs; horizontal 3-sum via 2 shuffles; h -> LDS (float4)
    const float4* __restrict__ A4 = reinterpret_cast<const float4*>(A);
    const float4* __restrict__ B4 = reinterpret_cast<const float4*>(B);
    #pragma unroll
    for (int k = 0; k < 4; ++k) {
        int e4 = t + k * 256;            // 0..1023, coalesced
        int r  = e4 >> 4;                // pixel row 0..63
        int g  = e4 & 15;                // float4 col-group 0..15
        float4 a = A4[e4];
        float4 b = B4[e4];
        float4 d;
        d.x = a.x - b.x; d.y = a.y - b.y; d.z = a.z - b.z; d.w = a.w - b.w;
        d.x *= d.x; d.y *= d.y; d.z *= d.z; d.w *= d.w;
        // neighbor group's first two elements (lane+1 holds group g+1 of same row;
        // g==15 lanes get wrapped garbage but are poisoned below)
        float nx = __shfl_down(d.x, 1);
        float ny = __shfl_down(d.y, 1);
        float4 h;
        h.x = d.x + d.y + d.z;
        h.y = d.y + d.z + d.w;
        h.z = d.z + d.w + nx;
        h.w = d.w + nx + ny;
        if (g == 15) { h.z = 1e30f; h.w = 1e30f; }   // cols 62,63 invalid -> exp==0
        *reinterpret_cast<float4*>(&hl[r * HS + 4 * g]) = h;
    }
    __syncthreads();

    // pass 2: thread (g, rc) produces output rows 4rc..4rc+3 for cols 4g..4g+3
    const int g2 = t & 15, rc = t >> 4;
    float4 hr[6];
    #pragma unroll
    for (int rr = 0; rr < 6; ++rr) {
        int row = 4 * rc + rr;
        row = (row < 64) ? row : 63;               // clamped reads feed masked rows only
        hr[rr] = *reinterpret_cast<const float4*>(&hl[row * HS + 4 * g2]);
    }

    const float NEG_SCALE = -1.0f / (40.5f * 0.69314718055994530942f);  // exp2 scale
    float4 acc; acc.x = acc.y = acc.z = acc.w = 0.0f;
    #pragma unroll
    for (int o = 0; o < 4; ++o) {
        float4 D;
        D.x = hr[o].x + hr[o + 1].x + hr[o + 2].x;
        D.y = hr[o].y + hr[o + 1].y + hr[o + 2].y;
        D.z = hr[o].z + hr[o + 1].z + hr[o + 2].z;
        D.w = hr[o].w + hr[o + 1].w + hr[o + 2].w;
        if (4 * rc + o < 62) {                     // valid output row
            acc.x += EXP2F(D.x * NEG_SCALE);
            acc.y += EXP2F(D.y * NEG_SCALE);
            acc.z += EXP2F(D.z * NEG_SCALE);
            acc.w += EXP2F(D.w * NEG_SCALE);
        }
    }

    double lsum = ((double)acc.x + (double)acc.y) + ((double)acc.z + (double)acc.w);

    // deterministic wave reduce (64 lanes), then 4 wave partials
    #pragma unroll
    for (int off = 32; off > 0; off >>= 1)
        lsum += __shfl_down(lsum, off);
    const int lane = t & 63, wid = t >> 6;
    if (lane == 0) wsum[wid] = lsum;
    __syncthreads();
    if (t == 0)
        partials[bid] = wsum[0] + wsum[1] + wsum[2] + wsum[3];
}

__global__ __launch_bounds__(256) void mmd_reduce_kernel(
    const double* __restrict__ partials, float* __restrict__ out)
{
    const int t = threadIdx.x;
    double a0 = 0.0, a1 = 0.0, a2 = 0.0;
    for (int e = t; e < NPAIR_TRI; e += 256) a0 += partials[e];                  // xx, i<j
    for (int e = t; e < NPAIR_TRI; e += 256) a1 += partials[NPAIR_TRI + e];      // yy, i<j
    for (int e = t; e < 4096;      e += 256) a2 += partials[2 * NPAIR_TRI + e];  // xy, all

    __shared__ double w[3][4];
    const int lane = t & 63, wid = t >> 6;
    double v;
    v = a0;
    #pragma unroll
    for (int off = 32; off > 0; off >>= 1) v += __shfl_down(v, off);
    if (lane == 0) w[0][wid] = v;
    v = a1;
    #pragma unroll
    for (int off = 32; off > 0; off >>= 1) v += __shfl_down(v, off);
    if (lane == 0) w[1][wid] = v;
    v = a2;
    #pragma unroll
    for (int off = 32; off > 0; off >>= 1) v += __shfl_down(v, off);
    if (lane == 0) w[2][wid] = v;
    __syncthreads();
    if (t == 0) {
        double sxx = w[0][0] + w[0][1] + w[0][2] + w[0][3];   // half of off-diag sum
        double syy = w[1][0] + w[1][1] + w[1][2] + w[1][3];
        double sxy = w[2][0] + w[2][1] + w[2][2] + w[2][3];
        const double cnt_off = 64.0 * 63.0 * 62.0 * 62.0;     // N*(N-1)*h*w
        const double cnt_all = 64.0 * 64.0 * 62.0 * 62.0;     // N*N*h*w
        out[0] = (float)(2.0 * sxx / cnt_off - 2.0 * sxy / cnt_all + 2.0 * syy / cnt_off);
    }
}

extern "C" void kernel_launch(void* const* d_in, const int* in_sizes, int n_in,
                              void* d_out, int out_size, void* d_ws, size_t ws_size,
                              hipStream_t stream) {
    const float* x = (const float*)d_in[0];
    const float* y = (const float*)d_in[1];
    float* out = (float*)d_out;
    double* partials = (double*)d_ws;   // 8128 doubles = 63.5 KiB

    mmd_pair_kernel<<<2 * NPAIR_TRI + 4096, 256, 0, stream>>>(x, y, partials);
    mmd_reduce_kernel<<<1, 256, 0, stream>>>(partials, out);
}

// Round 4
// 22.226 us; speedup vs baseline: 2.2206x; 1.3601x over previous
//
#include <hip/hip_runtime.h>

// PatchMMD: x,y are (64,1,64,64) fp32. For pairs (i,j):
//   D(i,j,p,q) = sum_{3x3 window at (p,q)} (A_i - B_j)^2   (VALID -> 62x62)
//   K = exp(-D / (2*(0.5*9)^2)) = exp(-D/40.5)
// out = offdiag_mean(Kxx) - 2*mean(Kxy) + offdiag_mean(Kyy)
//
// Round 4 structure:
//  - all cross-lane ops via DPP (VALU), zero ds_bpermute/ds_swizzle:
//    * horizontal halo: row_shl:1 (lane+1 within 16-lane DPP row)
//    * wave reduce: row_shr:{1,2,4,8} Kogge-Stone on fp64 halves
//  - LDS ops per thread: 4 b128 h-writes + 6 b128 h-reads + 1 masked b64
//  - pass 2 sliding 3-row window (low VGPR -> 8 waves/SIMD)
//  - fp64 accumulation from per-thread fp32x4 partials onward

#define HW 4096          // 64*64 pixels per image
#define HS 68            // h LDS row stride in floats (16B-aligned, bank-staggered)
#define NPAIR_TRI 2016   // 64*63/2

#if __has_builtin(__builtin_amdgcn_exp2f)
#define EXP2F(v) __builtin_amdgcn_exp2f(v)
#else
#define EXP2F(v) __expf((v) * 0.69314718055994530942f)
#endif

// DPP move: CTRL 0x100+N = row_shl:N (lane i <- lane i+N within 16-lane row),
//           0x110+N = row_shr:N (lane i <- lane i-N). bound_ctrl -> 0 fill.
template<int CTRL>
__device__ __forceinline__ float dpp_mov_f(float x) {
    int r = __builtin_amdgcn_update_dpp(0, __float_as_int(x), CTRL, 0xf, 0xf, true);
    return __int_as_float(r);
}
template<int CTRL>
__device__ __forceinline__ double dpp_mov_d(double x) {
    long long xi = __double_as_longlong(x);
    int lo = __builtin_amdgcn_update_dpp(0, (int)(xi & 0xffffffffLL), CTRL, 0xf, 0xf, true);
    int hi = __builtin_amdgcn_update_dpp(0, (int)(((unsigned long long)xi) >> 32), CTRL, 0xf, 0xf, true);
    long long r = (long long)(((unsigned long long)(unsigned)lo) |
                              (((unsigned long long)(unsigned)hi) << 32));
    return __longlong_as_double(r);
}

__global__ __launch_bounds__(256) void mmd_pair_kernel(
    const float* __restrict__ x, const float* __restrict__ y,
    double* __restrict__ partials)
{
    const int bid = blockIdx.x;
    const int t   = threadIdx.x;

    // block -> (type, i, j). [0,2016): xx i<j; [2016,4032): yy i<j; rest: xy all.
    int type, i, j;
    if (bid < 2 * NPAIR_TRI) {
        type = (bid < NPAIR_TRI) ? 0 : 1;
        int k = bid - type * NPAIR_TRI;
        int ii = 0;
        while (k >= 63 - ii) { k -= 63 - ii; ++ii; }   // uniform scalar loop
        i = ii; j = ii + 1 + k;
    } else {
        type = 2;
        int pair = bid - 2 * NPAIR_TRI;
        i = pair >> 6; j = pair & 63;
    }

    const float* __restrict__ A = (type == 1 ? y : x) + i * HW;
    const float* __restrict__ B = (type == 0 ? x : y) + j * HW;

    __shared__ float hl[64 * HS];
    __shared__ double rsum[16];

    // pass 1: d^2 in regs; horizontal 3-sum h via DPP row_shl:1; h -> LDS float4
    const float4* __restrict__ A4 = reinterpret_cast<const float4*>(A);
    const float4* __restrict__ B4 = reinterpret_cast<const float4*>(B);
    const int g = t & 15;             // float4 col-group == DPP row position
    #pragma unroll
    for (int k = 0; k < 4; ++k) {
        int e4 = t + k * 256;         // 0..1023, coalesced
        int r  = e4 >> 4;             // pixel row 0..63
        float4 a = A4[e4];
        float4 b = B4[e4];
        float dx = a.x - b.x, dy = a.y - b.y, dz = a.z - b.z, dw = a.w - b.w;
        dx *= dx; dy *= dy; dz *= dz; dw *= dw;
        float nx = dpp_mov_f<0x101>(dx);   // lane+1's d.x (0 for g==15, poisoned below)
        float ny = dpp_mov_f<0x101>(dy);   // lane+1's d.y
        float s1 = dy + dz;
        float s2 = dw + nx;
        float4 h;
        h.x = dx + s1;
        h.y = s1 + dw;
        h.z = dz + s2;
        h.w = s2 + ny;
        if (g == 15) { h.z = 1e30f; h.w = 1e30f; }   // cols 62,63 invalid -> exp==0
        *reinterpret_cast<float4*>(&hl[r * HS + 4 * g]) = h;
    }
    __syncthreads();

    // pass 2: thread (g2, rc) -> output rows 4rc..4rc+3, cols 4g2..4g2+3.
    // sliding 3-row window, ds_read_b128 each row once.
    const int g2 = t & 15, rc = t >> 4;
    const int base = 4 * g2;
    const int row0 = 4 * rc;
    const float NEG_SCALE = -1.0f / (40.5f * 0.69314718055994530942f);  // exp2 scale
    float accx = 0.0f, accy = 0.0f, accz = 0.0f, accw = 0.0f;

    float4 h0 = *reinterpret_cast<const float4*>(&hl[row0 * HS + base]);
    float4 h1 = *reinterpret_cast<const float4*>(&hl[(row0 + 1) * HS + base]);
    #pragma unroll
    for (int o = 0; o < 4; ++o) {
        int row = row0 + 2 + o;
        row = (row < 64) ? row : 63;               // clamped reads feed masked rows only
        float4 h2 = *reinterpret_cast<const float4*>(&hl[row * HS + base]);
        if (row0 + o < 62) {                       // valid output row
            accx += EXP2F((h0.x + h1.x + h2.x) * NEG_SCALE);
            accy += EXP2F((h0.y + h1.y + h2.y) * NEG_SCALE);
            accz += EXP2F((h0.z + h1.z + h2.z) * NEG_SCALE);
            accw += EXP2F((h0.w + h1.w + h2.w) * NEG_SCALE);
        }
        h0 = h1; h1 = h2;
    }

    double lsum = ((double)accx + (double)accy) + ((double)accz + (double)accw);

    // 16-lane in-row Kogge-Stone reduce on fp64 (pure VALU via DPP)
    lsum += dpp_mov_d<0x111>(lsum);   // row_shr:1
    lsum += dpp_mov_d<0x112>(lsum);   // row_shr:2
    lsum += dpp_mov_d<0x114>(lsum);   // row_shr:4
    lsum += dpp_mov_d<0x118>(lsum);   // row_shr:8  -> lane (l&15)==15 holds row sum
    if ((t & 15) == 15) rsum[t >> 4] = lsum;
    __syncthreads();
    if (t == 0) {
        double s = 0.0;
        #pragma unroll
        for (int k = 0; k < 16; ++k) s += rsum[k];
        partials[bid] = s;
    }
}

__global__ __launch_bounds__(1024) void mmd_reduce_kernel(
    const double* __restrict__ partials, float* __restrict__ out)
{
    const int t = threadIdx.x;
    // partials: [0,2016) xx i<j, [2016,4032) yy i<j, [4032,8128) xy all
    double a_off = 0.0, a_xy = 0.0;
    for (int e = t; e < 2 * NPAIR_TRI; e += 1024) a_off += partials[e];
    for (int e = t; e < 4096;          e += 1024) a_xy  += partials[2 * NPAIR_TRI + e];

    const double cnt_off = 64.0 * 63.0 * 62.0 * 62.0;     // N*(N-1)*h*w
    const double cnt_all = 64.0 * 64.0 * 62.0 * 62.0;     // N*N*h*w
    double v = a_off * (2.0 / cnt_off) - a_xy * (2.0 / cnt_all);

    v += dpp_mov_d<0x111>(v);
    v += dpp_mov_d<0x112>(v);
    v += dpp_mov_d<0x114>(v);
    v += dpp_mov_d<0x118>(v);         // lane (l&15)==15 holds 16-lane sum

    __shared__ double w[64];
    if ((t & 15) == 15) w[t >> 4] = v;
    __syncthreads();
    if (t == 0) {
        double s = 0.0;
        #pragma unroll
        for (int k = 0; k < 64; ++k) s += w[k];
        out[0] = (float)s;
    }
}

extern "C" void kernel_launch(void* const* d_in, const int* in_sizes, int n_in,
                              void* d_out, int out_size, void* d_ws, size_t ws_size,
                              hipStream_t stream) {
    const float* x = (const float*)d_in[0];
    const float* y = (const float*)d_in[1];
    float* out = (float*)d_out;
    double* partials = (double*)d_ws;   // 8128 doubles = 63.5 KiB

    mmd_pair_kernel<<<2 * NPAIR_TRI + 4096, 256, 0, stream>>>(x, y, partials);
    mmd_reduce_kernel<<<1, 1024, 0, stream>>>(partials, out);
}